// Round 9
// baseline (454.161 us; speedup 1.0000x reference)
//
#include <hip/hip_runtime.h>
#include <hip/hip_bf16.h>
#include <math.h>

#define BATCH 16384
#define NCAT 24

// log(1e-30f), log(16)
#define L30F  (-69.07755279f)
#define LOGKF (2.7725887f)

typedef __attribute__((ext_vector_type(8))) short short8;
typedef __attribute__((ext_vector_type(4))) float f32x4;

__device__ __forceinline__ float lae(float a, float b) {
    float m = fmaxf(a, b);
    return m + logf(expf(a - m) + expf(b - m));
}

__device__ __forceinline__ void glds16(const void* g, void* l) {
    __builtin_amdgcn_global_load_lds((const __attribute__((address_space(1))) void*)g,
                                     (__attribute__((address_space(3))) void*)l,
                                     16, 0, 0);
}

__device__ __forceinline__ void glds4(const void* g, void* l) {
    __builtin_amdgcn_global_load_lds((const __attribute__((address_space(1))) void*)g,
                                     (__attribute__((address_space(3))) void*)l,
                                     4, 0, 0);
}

// --- fused setup: 4x weight transpose + proj_w bf16 cast + E0 + colconst + sched
// blocks [0,3584): transposes {te_w1,te_w2,mlp_w1,mlp_w2} -> bf16 [Npad x 1024]
// blocks [3584,3808): pjb = bf16(proj_w) [448 x 1024], rows >= 400 zero
// blocks [3808,7808): E0 bf16 timestep-embedding table (1000x1024)
// blocks [7808,7812): colconst[j] = te_b2[j]+proj_b[j]+L30F*sum proj_w[16:400][j]; zbias=0
// block 7812: schedules + acc zero
__global__ __launch_bounds__(256) void setup_all(
    const float* __restrict__ s0, const float* __restrict__ s1,
    const float* __restrict__ s2, const float* __restrict__ s3,
    __hip_bfloat16* __restrict__ d0, __hip_bfloat16* __restrict__ d1,
    __hip_bfloat16* __restrict__ d2, __hip_bfloat16* __restrict__ d3,
    __hip_bfloat16* __restrict__ pjb,
    __hip_bfloat16* __restrict__ E0, const float* __restrict__ proj_w,
    const float* __restrict__ proj_b, const float* __restrict__ te_b2,
    float* __restrict__ colconst, float* __restrict__ zbias,
    float* __restrict__ sched, double* __restrict__ acc) {
    const int bid = blockIdx.x, tid = threadIdx.x;
    if (bid < 3584) {
        // transpose: W[K x Nw] f32 -> Wt[Npad x 1024] bf16 (zero pad)
        const int boff[5] = {0, 1024, 2048, 3072, 3584};
        const int nxs[4]  = {32, 32, 32, 16};
        const int Nws[4]  = {1024, 1024, 1024, 400};
        const int Nps[4]  = {1024, 1024, 1024, 512};
        int job = 0;
#pragma unroll
        for (int j = 1; j < 4; ++j) job += (bid >= boff[j]) ? 1 : 0;
        const float* W = (job == 0) ? s0 : (job == 1) ? s1 : (job == 2) ? s2 : s3;
        __hip_bfloat16* Wt = (job == 0) ? d0 : (job == 1) ? d1 : (job == 2) ? d2 : d3;
        const int lb = bid - boff[job];
        const int Nw = Nws[job], Npad = Nps[job];
        const int n0 = (lb % nxs[job]) * 32, k0 = (lb / nxs[job]) * 32;
        __shared__ float t[32][33];
        int c = tid & 31, r8 = tid >> 5;
#pragma unroll
        for (int i = 0; i < 32; i += 8) {
            int k = k0 + r8 + i, n = n0 + c;
            t[r8 + i][c] = (n < Nw) ? W[(size_t)k * Nw + n] : 0.0f;
        }
        __syncthreads();
#pragma unroll
        for (int i = 0; i < 32; i += 8) {
            int n = n0 + r8 + i, k = k0 + c;
            if (n < Npad) Wt[(size_t)n * 1024 + k] = __float2bfloat16(t[c][r8 + i]);
        }
    } else if (bid < 3808) {
        int idx = (bid - 3584) * 2048 + tid * 8;
        int r = idx >> 10;
        __hip_bfloat16 v[8];
        if (r < 400) {
            const float* src = proj_w + idx;
#pragma unroll
            for (int q = 0; q < 8; ++q) v[q] = __float2bfloat16(src[q]);
        } else {
#pragma unroll
            for (int q = 0; q < 8; ++q) v[q] = __float2bfloat16(0.0f);
        }
        *(short8*)(pjb + idx) = *(const short8*)v;
    } else if (bid < 7808) {
        int gid = (bid - 3808) * 256 + tid;
        int t = gid >> 10, j = gid & 1023;
        int jj = (j < 512) ? j : j - 512;
        float freq = expf(-logf(10000.0f) * (float)jj / 512.0f);
        float arg = (float)t * freq;
        E0[gid] = __float2bfloat16((j < 512) ? cosf(arg) : sinf(arg));
    } else if (bid < 7812) {
        int j = (bid - 7808) * 256 + tid;
        float s = 0.0f;
        for (int r = 16; r < 400; ++r) s += proj_w[(size_t)r * 1024 + j];
        colconst[j] = te_b2[j] + proj_b[j] + L30F * s;
        zbias[j] = 0.0f;
    } else {
        __shared__ double la_s[1000];
        __shared__ double lca_s[1000];
        const double PI = 3.14159265358979323846;
        for (int i = tid; i < 1000; i += 256) {
            double u0 = ((double)i / 1000.0 + 0.008) / 1.008 * PI * 0.5;
            double u1 = ((double)(i + 1) / 1000.0 + 0.008) / 1.008 * PI * 0.5;
            double c0 = cos(u0), c1 = cos(u1);
            double beta = 1.0 - (c1 * c1) / (c0 * c0);
            if (beta > 0.999) beta = 0.999;
            la_s[i] = log(1.0 - beta);
        }
        __syncthreads();
        if (tid == 0) {
            double run = 0.0;
            for (int i = 0; i < 1000; ++i) { run += la_s[i]; lca_s[i] = run; }
            *acc = 0.0;
        }
        __syncthreads();
        for (int i = tid; i < 1000; i += 256) {
            double la = la_s[i], lca = lca_s[i];
            sched[i]        = (float)la;
            sched[1000 + i] = (float)log(1.0 - exp(la) + 1e-40);
            sched[2000 + i] = (float)lca;
            sched[3000 + i] = (float)log(1.0 - exp(lca) + 1e-40);
            sched[4000 + i] = (float)sqrt(exp(lca));
            sched[5000 + i] = (float)sqrt(1.0 - exp(lca));
        }
    }
}

// ------------------------------------------------------------ bf16 MFMA GEMM
// C[M,Nreal] = epi(A[M,Kd] @ Bt^T + bias), A row-major bf16, Bt [Npad x Kd] bf16.
// TILE x TILE block tile, BK=32, 4 waves (2x2), FM x FM frags of 16x16x32 MFMA.
// XCD-aware swizzle. EPI: 1 = silu + bf16, 5 = plain bf16 store,
// 6 = +embrow[t[m]][n] (bf16 table, LDS-gathered under K-loop) + relu + bf16,
// 4 = fused loss: acc -> LDS scoreboard -> per-(row,cat) loss (no store).
template <int EPI, int TILE>
__global__ __launch_bounds__(256) void gemm_mfma(
    const __hip_bfloat16* __restrict__ A, const __hip_bfloat16* __restrict__ Bt,
    const float* __restrict__ bias, void* __restrict__ Cout,
    int M, int Kd, int Nreal, int Cstride,
    const int* __restrict__ tidx, const float* __restrict__ rowbias,
    const int* __restrict__ x_cat, const int* __restrict__ t_in,
    const int* __restrict__ hot, const float* __restrict__ noise,
    const float* __restrict__ sched, double* __restrict__ acc_out) {
    constexpr int FM  = TILE / 32;   // MFMA frags per wave per dim
    constexpr int CPM = TILE / 16;   // 16-row staging chunks per matrix
    constexpr int CPW = TILE / 32;   // staging chunks per wave
    constexpr int STAGE = 4 * TILE * 32;  // As+Bs bytes
    constexpr int SMEM_BYTES = (EPI == 4) ? 65536
                               : (EPI == 6) ? (STAGE + TILE * TILE * 2)
                               : STAGE;
    __shared__ __align__(16) char SMEM[SMEM_BYTES];
    __hip_bfloat16* As = (__hip_bfloat16*)SMEM;
    __hip_bfloat16* Bs = As + TILE * 32;

    const int tid = threadIdx.x;
    const int lane = tid & 63, wave = tid >> 6;
    const int wm = wave >> 1, wn = wave & 1;

    // XCD swizzle (same-m n-blocks consecutive within one XCD)
    int mb, nb;
    {
        int nbx = gridDim.x, nby = gridDim.y;
        int b = blockIdx.y * nbx + blockIdx.x;
        if ((nby & 7) == 0) {
            int x = b & 7, g = b >> 3;
            nb = g % nbx;
            mb = x + 8 * (g / nbx);
        } else { mb = blockIdx.y; nb = blockIdx.x; }
    }
    const int m0 = mb * TILE, n0 = nb * TILE;

    const __hip_bfloat16* gsrc[CPW];
    char* ldst[CPW];
#pragma unroll
    for (int ii = 0; ii < CPW; ++ii) {
        int gc = wave * CPW + ii;
        int mat = gc / CPM, rem = gc % CPM;
        int row = rem * 16 + (lane >> 2);
        int col = (lane & 3) * 8;
        if (mat == 0) {
            int r = m0 + row; if (r > M - 1) r = M - 1;   // clamp; stores guarded
            gsrc[ii] = A + (size_t)r * Kd + col;
            ldst[ii] = (char*)As + rem * 1024;
        } else {
            int r = n0 + row;                             // Bt padded to tile
            gsrc[ii] = Bt + (size_t)r * Kd + col;
            ldst[ii] = (char*)Bs + rem * 1024;
        }
    }

    // EPI==6: gather this block's 128 rowbias rows (bf16) into LDS. Issued
    // before the K-loop; the first barrier's vmcnt(0) drains them -> latency
    // hidden under MFMA. NOTE: global address must be PER-LANE (base + lane*4B);
    // the LDS side is wave-uniform base + lane*4 (m104/m108 semantics).
    if (EPI == 6) {
        char* LE = SMEM + STAGE;
        const __hip_bfloat16* embp = (const __hip_bfloat16*)rowbias;
        for (int r = wave * (TILE / 4); r < (wave + 1) * (TILE / 4); ++r) {
            int trow = tidx[m0 + r];   // loop-uniform -> scalarized
            glds4((const char*)(embp + (size_t)trow * 1024 + n0 + lane * 2),
                  LE + r * (TILE * 2));
        }
    }

    f32x4 acc[FM][FM] = {};
    const int q8 = (lane >> 4) * 8;
    const int l15 = lane & 15;

    for (int k0 = 0; k0 < Kd; k0 += 32) {
#pragma unroll
        for (int ii = 0; ii < CPW; ++ii) glds16(gsrc[ii] + k0, ldst[ii]);
        __syncthreads();
        short8 af[FM], bfr[FM];
#pragma unroll
        for (int i = 0; i < FM; ++i) {
            af[i]  = *(const short8*)(As + (size_t)(wm * (TILE / 2) + i * 16 + l15) * 32 + q8);
            bfr[i] = *(const short8*)(Bs + (size_t)(wn * (TILE / 2) + i * 16 + l15) * 32 + q8);
        }
#pragma unroll
        for (int i = 0; i < FM; ++i)
#pragma unroll
            for (int j = 0; j < FM; ++j)
                acc[i][j] = __builtin_amdgcn_mfma_f32_16x16x32_bf16(
                    af[i], bfr[j], acc[i][j], 0, 0, 0);
        __syncthreads();
    }

    if (EPI == 4) {
        // Phase 1: dump raw acc to LDS scoreboard S[128][128] (f32, swizzled
        // col' = (col+row)&127). acc dies here -> no spill in K-loop.
        float* S = (float*)SMEM;
#pragma unroll
        for (int i = 0; i < FM; ++i) {
            int rbase = wm * (TILE / 2) + i * 16 + (lane >> 4) * 4;
#pragma unroll
            for (int j = 0; j < FM; ++j) {
                int lcol = wn * (TILE / 2) + j * 16 + l15;
#pragma unroll
                for (int r = 0; r < 4; ++r) {
                    int row = rbase + r;
                    S[row * 128 + ((lcol + row) & 127)] = acc[i][j][r];
                }
            }
        }
        __syncthreads();

        // Phase 2: one (row, col-group) pair per thread-iteration.
        double local = 0.0;
        const float* LOG_A = sched;
        const float* LOG_1M_A = sched + 1000;
        const float* LOG_CA = sched + 2000;
        const float* LOG_1M_CA = sched + 3000;
#pragma unroll
        for (int it = 0; it < 4; ++it) {
            int p = it * 256 + tid;
            int ml = p & 127, cg = p >> 7;
            int colbase = n0 + cg * 16;
            if (colbase >= 400) continue;     // zero-pad cols
            int m = m0 + ml;
            float ocv[16];
#pragma unroll
            for (int k = 0; k < 16; ++k)
                ocv[k] = S[ml * 128 + ((cg * 16 + k + ml) & 127)] + bias[colbase + k];
            if (colbase == 0) {
                // gaussian block
#pragma unroll
                for (int k = 0; k < 16; ++k) {
                    float d = noise[(size_t)m * 16 + k] - ocv[k];
                    local += (double)(d * d) * (1.0 / (16.0 * BATCH));
                }
            } else {
                int c = (colbase - 16) >> 4;
                int t = t_in[m];
                int xc = x_cat[m * 24 + c];
                int s = hot[m * 24 + c];
                float mx = -3e38f;
#pragma unroll
                for (int k = 0; k < 16; ++k) mx = fmaxf(mx, ocv[k]);
                float sm = 0.0f;
#pragma unroll
                for (int k = 0; k < 16; ++k) sm += expf(ocv[k] - mx);
                float lse = mx + logf(sm);
                int tm1 = (t > 0) ? t - 1 : 0;
                float lca1 = LOG_CA[tm1];
                float l1m1 = LOG_1M_CA[tm1] - LOGKF;
                float la = LOG_A[t];
                float l1a = LOG_1M_A[t] - LOGKF;
                float qh = lae(la, l1a);
                float qo = lae(L30F + la, l1a);
                float levh = (t == 0) ? 0.0f : lae(lca1, l1m1);
                float levo = (t == 0) ? L30F : lae(L30F + lca1, l1m1);
                float un[16], ut[16];
                float mu = -3e38f, mt2 = -3e38f;
#pragma unroll
                for (int k = 0; k < 16; ++k) {
                    float lxh = ocv[k] - lse;
                    float lev = (t == 0) ? lxh : lae(lxh + lca1, l1m1);
                    float q = (k == s) ? qh : qo;
                    un[k] = lev + q;
                    ut[k] = ((k == xc) ? levh : levo) + q;
                    mu = fmaxf(mu, un[k]);
                    mt2 = fmaxf(mt2, ut[k]);
                }
                float su = 0.0f, st = 0.0f;
#pragma unroll
                for (int k = 0; k < 16; ++k) { su += expf(un[k] - mu); st += expf(ut[k] - mt2); }
                float lsu = mu + logf(su), lst = mt2 + logf(st);
                float kl = 0.0f, dn = 0.0f;
#pragma unroll
                for (int k = 0; k < 16; ++k) {
                    float lmp = un[k] - lsu;
                    float ltp = ut[k] - lst;
                    kl += expf(ltp) * (ltp - lmp);
                    dn -= ((k == xc) ? 1.0f : 1e-30f) * lmp;
                }
                float Lt = (t == 0) ? dn : kl;
                local += (double)Lt * (1.0 / (24.0 * BATCH));
            }
        }
        // block reduction (wred aliases S after sync)
        for (int off = 32; off > 0; off >>= 1)
            local += __shfl_down(local, off);
        __syncthreads();
        double* wred = (double*)SMEM;
        if (lane == 0) wred[wave] = local;
        __syncthreads();
        if (tid == 0)
            atomicAdd(acc_out, wred[0] + wred[1] + wred[2] + wred[3]);
        return;
    }

    const __hip_bfloat16* LE = (const __hip_bfloat16*)(SMEM + STAGE);
#pragma unroll
    for (int i = 0; i < FM; ++i) {
        int mlbase = wm * (TILE / 2) + i * 16 + (lane >> 4) * 4;
#pragma unroll
        for (int j = 0; j < FM; ++j) {
            int nl = wn * (TILE / 2) + j * 16 + l15;
            int n = n0 + nl;
            if (n >= Nreal) continue;
            float bv = bias[n];
#pragma unroll
            for (int r = 0; r < 4; ++r) {
                int ml = mlbase + r;
                int m = m0 + ml;
                if (m >= M) continue;
                float v = acc[i][j][r] + bv;
                if (EPI == 1) v = v / (1.0f + expf(-v));
                if (EPI == 6) { v += __bfloat162float(LE[ml * TILE + nl]); v = fmaxf(v, 0.0f); }
                ((__hip_bfloat16*)Cout)[(size_t)m * Cstride + n] = __float2bfloat16(v);
            }
        }
    }
}

// ----------------------- per-row prep: gumbel argmax + build X[B x 416] bf16
// X = [x_num_t (16) | delta-onehot*69.0776 (384) | zeros (16)]
__global__ __launch_bounds__(256) void prep_x(
    const float* __restrict__ x_num, const int* __restrict__ x_cat,
    const int* __restrict__ t_in, const float* __restrict__ noise,
    const float* __restrict__ gum, const float* __restrict__ sched,
    __hip_bfloat16* __restrict__ X, int* __restrict__ hot) {
    __shared__ float xnt[16][16];
    __shared__ int sh_hot[16][24];
    __shared__ int sh_t[16];
    const int b0 = blockIdx.x * 16;
    const int tid = threadIdx.x;
    const float* LOG_CA = sched + 2000;
    const float* LOG_1M_CA = sched + 3000;
    const float* SQ_AC = sched + 4000;
    const float* SQ_1M = sched + 5000;
    if (tid < 16) sh_t[tid] = t_in[b0 + tid];
    __syncthreads();
    {
        int r = tid >> 4, i = tid & 15;
        int t = sh_t[r];
        xnt[r][i] = SQ_AC[t] * x_num[(size_t)(b0 + r) * 16 + i] +
                    SQ_1M[t] * noise[(size_t)(b0 + r) * 16 + i];
    }
    for (int task = tid; task < 16 * 24; task += 256) {
        int r = task / 24, c = task - r * 24;
        int t = sh_t[r];
        int xc = x_cat[(size_t)(b0 + r) * 24 + c];
        float l1 = LOG_1M_CA[t] - LOGKF;
        float lca = LOG_CA[t];
        float vh = lae(lca, l1);
        float vo = lae(L30F + lca, l1);
        const float* gu = gum + (size_t)(b0 + r) * 384 + c * 16;
        float best = -3.0e38f;
        int bi = 0;
#pragma unroll
        for (int k = 0; k < 16; ++k) {
            float g = -logf(-logf(gu[k] + 1e-30f) + 1e-30f);
            float v = g + ((k == xc) ? vh : vo);
            if (v > best) { best = v; bi = k; }
        }
        sh_hot[r][c] = bi;
        hot[(size_t)(b0 + r) * 24 + c] = bi;
    }
    __syncthreads();
    const float DELTA = 69.07755279f;  // -L30F
#pragma unroll
    for (int it = 0; it < 4; ++it) {
        int idx = it * 256 + tid;          // need 16*52 = 832 short8 stores
        if (idx < 832) {
            int r = idx / 52, jc = idx - r * 52;
            int j0 = jc * 8;
            __hip_bfloat16 v[8];
#pragma unroll
            for (int qq = 0; qq < 8; ++qq) {
                int j = j0 + qq;
                float f = 0.0f;
                if (j < 16) {
                    f = xnt[r][j];
                } else if (j < 400) {
                    int c = (j - 16) >> 4, k = (j - 16) & 15;
                    f = (sh_hot[r][c] == k) ? DELTA : 0.0f;
                }
                v[qq] = __float2bfloat16(f);
            }
            *(short8*)(X + (size_t)(b0 + r) * 416 + j0) = *(const short8*)v;
        }
    }
}

__global__ void finalize_kernel(const double* __restrict__ acc,
                                const float* __restrict__ sched,
                                float* __restrict__ out) {
    // kl_prior is identical for every (sample, category): add once.
    float lcaT = sched[2999];
    float l1mT = sched[3999] - LOGKF;
    float ph = lae(lcaT, l1mT);
    float po = lae(L30F + lcaT, l1mT);
    float prior = expf(ph) * (ph + LOGKF) + 15.0f * expf(po) * (po + LOGKF);
    out[0] = (float)(*acc + (double)prior);
}

extern "C" void kernel_launch(void* const* d_in, const int* in_sizes, int n_in,
                              void* d_out, int out_size, void* d_ws, size_t ws_size,
                              hipStream_t stream) {
    const float* x_num  = (const float*)d_in[0];
    const int*   x_cat  = (const int*)d_in[1];
    const int*   t_in   = (const int*)d_in[2];
    const float* noise  = (const float*)d_in[3];
    const float* gum    = (const float*)d_in[4];
    const float* te_w1  = (const float*)d_in[5];
    const float* te_b1  = (const float*)d_in[6];
    const float* te_w2  = (const float*)d_in[7];
    const float* te_b2  = (const float*)d_in[8];
    const float* proj_w = (const float*)d_in[9];
    const float* proj_b = (const float*)d_in[10];
    const float* mlp_w1 = (const float*)d_in[11];
    const float* mlp_b1 = (const float*)d_in[12];
    const float* mlp_w2 = (const float*)d_in[13];
    const float* mlp_b2 = (const float*)d_in[14];
    float* out = (float*)d_out;

    char* w = (char*)d_ws;
    size_t off = 0;
    auto alloc = [&](size_t bytes) {
        void* p = w + off;
        off += (bytes + 1023) & ~(size_t)1023;
        return p;
    };
    double* acc     = (double*)alloc(1024);
    float* sched    = (float*)alloc(6 * 1000 * 4);
    int*   hot      = (int*)alloc((size_t)BATCH * 24 * 4);
    float* colconst = (float*)alloc(1024 * 4);
    float* zbias    = (float*)alloc(1024 * 4);
    __hip_bfloat16* E0    = (__hip_bfloat16*)alloc((size_t)1024 * 1024 * 2);
    __hip_bfloat16* E1    = (__hip_bfloat16*)alloc((size_t)1024 * 1024 * 2);
    __hip_bfloat16* EMBp  = (__hip_bfloat16*)alloc((size_t)1024 * 1024 * 2);
    __hip_bfloat16* EMB2  = (__hip_bfloat16*)alloc((size_t)1024 * 1024 * 2);
    __hip_bfloat16* tw1t  = (__hip_bfloat16*)alloc((size_t)1024 * 1024 * 2);
    __hip_bfloat16* tw2t  = (__hip_bfloat16*)alloc((size_t)1024 * 1024 * 2);
    __hip_bfloat16* w1t   = (__hip_bfloat16*)alloc((size_t)1024 * 1024 * 2);
    __hip_bfloat16* w2t   = (__hip_bfloat16*)alloc((size_t)512 * 1024 * 2);
    __hip_bfloat16* pjb   = (__hip_bfloat16*)alloc((size_t)448 * 1024 * 2);
    __hip_bfloat16* PWT   = (__hip_bfloat16*)alloc((size_t)1024 * 416 * 2);
    __hip_bfloat16* X     = (__hip_bfloat16*)alloc((size_t)BATCH * 416 * 2);
    __hip_bfloat16* R     = (__hip_bfloat16*)alloc((size_t)BATCH * 1024 * 2);

    // setup: 4 transposes + pjb cast + E0 table + colconst/zbias + schedules
    setup_all<<<7813, 256, 0, stream>>>(te_w1, te_w2, mlp_w1, mlp_w2,
                                        tw1t, tw2t, w1t, w2t, pjb,
                                        E0, proj_w, proj_b, te_b2,
                                        colconst, zbias, sched, acc);
    // X + hot
    prep_x<<<BATCH / 16, 256, 0, stream>>>(x_num, x_cat, t_in, noise, gum, sched, X, hot);
    // PWT[j,k] = sum_n w1[n,j] proj_w[k,n]  -> [1024 x 416] bf16
    gemm_mfma<5, 64><<<dim3(7, 16), 256, 0, stream>>>(
        w1t, pjb, zbias, PWT, 1024, 1024, 416, 416,
        nullptr, nullptr, nullptr, nullptr, nullptr, nullptr, nullptr, nullptr);
    // E1 = silu(E0 @ te_w1 + te_b1)
    gemm_mfma<1, 64><<<dim3(16, 16), 256, 0, stream>>>(
        E0, tw1t, te_b1, E1, 1000, 1024, 1024, 1024,
        nullptr, nullptr, nullptr, nullptr, nullptr, nullptr, nullptr, nullptr);
    // EMBp = E1 @ te_w2 + (te_b2 + proj_b + L30F*catsum)   [all h-space consts]
    gemm_mfma<5, 64><<<dim3(16, 16), 256, 0, stream>>>(
        E1, tw2t, colconst, EMBp, 1000, 1024, 1024, 1024,
        nullptr, nullptr, nullptr, nullptr, nullptr, nullptr, nullptr, nullptr);
    // EMB2 = EMBp @ w1 + b1   [per-t hidden-layer bias table]
    gemm_mfma<5, 64><<<dim3(16, 16), 256, 0, stream>>>(
        EMBp, w1t, mlp_b1, EMB2, 1000, 1024, 1024, 1024,
        nullptr, nullptr, nullptr, nullptr, nullptr, nullptr, nullptr, nullptr);
    // R = relu(X @ PWT^T + EMB2[t])   [the old h-GEMM + R-GEMM, collapsed]
    gemm_mfma<6, 128><<<dim3(8, 128), 256, 0, stream>>>(
        X, PWT, zbias, R, BATCH, 416, 1024, 1024,
        t_in, (const float*)EMB2, nullptr, nullptr, nullptr, nullptr, nullptr, nullptr);
    // fused: (R @ mlp_w2 + mlp_b2) -> LDS scoreboard -> loss (no store)
    gemm_mfma<4, 128><<<dim3(4, 128), 256, 0, stream>>>(
        R, w2t, mlp_b2, nullptr, BATCH, 1024, 400, 0,
        nullptr, nullptr, x_cat, t_in, hot, noise, sched, acc);
    finalize_kernel<<<1, 1, 0, stream>>>(acc, sched, out);
}

// Round 10
// 305.624 us; speedup vs baseline: 1.4860x; 1.4860x over previous
//
#include <hip/hip_runtime.h>
#include <hip/hip_bf16.h>
#include <math.h>

#define BATCH 16384
#define NCAT 24

// log(1e-30f), log(16)
#define L30F  (-69.07755279f)
#define LOGKF (2.7725887f)

typedef __attribute__((ext_vector_type(8))) short short8;
typedef __attribute__((ext_vector_type(4))) float f32x4;

__device__ __forceinline__ float lae(float a, float b) {
    float m = fmaxf(a, b);
    return m + logf(expf(a - m) + expf(b - m));
}

__device__ __forceinline__ void glds16(const void* g, void* l) {
    __builtin_amdgcn_global_load_lds((const __attribute__((address_space(1))) void*)g,
                                     (__attribute__((address_space(3))) void*)l,
                                     16, 0, 0);
}

// --- fused setup: 4x weight transpose + proj_w bf16 cast + E0 + colconst + sched
// blocks [0,3584): transposes {te_w1,te_w2,mlp_w1,mlp_w2} -> bf16 [Npad x 1024]
// blocks [3584,3808): pjb = bf16(proj_w) [448 x 1024], rows >= 400 zero
// blocks [3808,7808): E0 bf16 timestep-embedding table (1000x1024)
// blocks [7808,7812): colconst[j] = te_b2[j]+proj_b[j]+L30F*sum proj_w[16:400][j]; zbias=0
// block 7812: schedules + acc zero
__global__ __launch_bounds__(256) void setup_all(
    const float* __restrict__ s0, const float* __restrict__ s1,
    const float* __restrict__ s2, const float* __restrict__ s3,
    __hip_bfloat16* __restrict__ d0, __hip_bfloat16* __restrict__ d1,
    __hip_bfloat16* __restrict__ d2, __hip_bfloat16* __restrict__ d3,
    __hip_bfloat16* __restrict__ pjb,
    __hip_bfloat16* __restrict__ E0, const float* __restrict__ proj_w,
    const float* __restrict__ proj_b, const float* __restrict__ te_b2,
    float* __restrict__ colconst, float* __restrict__ zbias,
    float* __restrict__ sched, double* __restrict__ acc) {
    const int bid = blockIdx.x, tid = threadIdx.x;
    if (bid < 3584) {
        // transpose: W[K x Nw] f32 -> Wt[Npad x 1024] bf16 (zero pad)
        const int boff[5] = {0, 1024, 2048, 3072, 3584};
        const int nxs[4]  = {32, 32, 32, 16};
        const int Nws[4]  = {1024, 1024, 1024, 400};
        const int Nps[4]  = {1024, 1024, 1024, 512};
        int job = 0;
#pragma unroll
        for (int j = 1; j < 4; ++j) job += (bid >= boff[j]) ? 1 : 0;
        const float* W = (job == 0) ? s0 : (job == 1) ? s1 : (job == 2) ? s2 : s3;
        __hip_bfloat16* Wt = (job == 0) ? d0 : (job == 1) ? d1 : (job == 2) ? d2 : d3;
        const int lb = bid - boff[job];
        const int Nw = Nws[job], Npad = Nps[job];
        const int n0 = (lb % nxs[job]) * 32, k0 = (lb / nxs[job]) * 32;
        __shared__ float t[32][33];
        int c = tid & 31, r8 = tid >> 5;
#pragma unroll
        for (int i = 0; i < 32; i += 8) {
            int k = k0 + r8 + i, n = n0 + c;
            t[r8 + i][c] = (n < Nw) ? W[(size_t)k * Nw + n] : 0.0f;
        }
        __syncthreads();
#pragma unroll
        for (int i = 0; i < 32; i += 8) {
            int n = n0 + r8 + i, k = k0 + c;
            if (n < Npad) Wt[(size_t)n * 1024 + k] = __float2bfloat16(t[c][r8 + i]);
        }
    } else if (bid < 3808) {
        int idx = (bid - 3584) * 2048 + tid * 8;
        int r = idx >> 10;
        __hip_bfloat16 v[8];
        if (r < 400) {
            const float* src = proj_w + idx;
#pragma unroll
            for (int q = 0; q < 8; ++q) v[q] = __float2bfloat16(src[q]);
        } else {
#pragma unroll
            for (int q = 0; q < 8; ++q) v[q] = __float2bfloat16(0.0f);
        }
        *(short8*)(pjb + idx) = *(const short8*)v;
    } else if (bid < 7808) {
        int gid = (bid - 3808) * 256 + tid;
        int t = gid >> 10, j = gid & 1023;
        int jj = (j < 512) ? j : j - 512;
        float freq = expf(-logf(10000.0f) * (float)jj / 512.0f);
        float arg = (float)t * freq;
        E0[gid] = __float2bfloat16((j < 512) ? cosf(arg) : sinf(arg));
    } else if (bid < 7812) {
        int j = (bid - 7808) * 256 + tid;
        float s = 0.0f;
        for (int r = 16; r < 400; ++r) s += proj_w[(size_t)r * 1024 + j];
        colconst[j] = te_b2[j] + proj_b[j] + L30F * s;
        zbias[j] = 0.0f;
    } else {
        __shared__ double la_s[1000];
        __shared__ double lca_s[1000];
        const double PI = 3.14159265358979323846;
        for (int i = tid; i < 1000; i += 256) {
            double u0 = ((double)i / 1000.0 + 0.008) / 1.008 * PI * 0.5;
            double u1 = ((double)(i + 1) / 1000.0 + 0.008) / 1.008 * PI * 0.5;
            double c0 = cos(u0), c1 = cos(u1);
            double beta = 1.0 - (c1 * c1) / (c0 * c0);
            if (beta > 0.999) beta = 0.999;
            la_s[i] = log(1.0 - beta);
        }
        __syncthreads();
        if (tid == 0) {
            double run = 0.0;
            for (int i = 0; i < 1000; ++i) { run += la_s[i]; lca_s[i] = run; }
            *acc = 0.0;
        }
        __syncthreads();
        for (int i = tid; i < 1000; i += 256) {
            double la = la_s[i], lca = lca_s[i];
            sched[i]        = (float)la;
            sched[1000 + i] = (float)log(1.0 - exp(la) + 1e-40);
            sched[2000 + i] = (float)lca;
            sched[3000 + i] = (float)log(1.0 - exp(lca) + 1e-40);
            sched[4000 + i] = (float)sqrt(exp(lca));
            sched[5000 + i] = (float)sqrt(1.0 - exp(lca));
        }
    }
}

// ------------------------------------------------------------ bf16 MFMA GEMM
// C[M,Nreal] = epi(A[M,Kd] @ Bt^T + bias), A row-major bf16, Bt [Npad x Kd] bf16.
// TILE x TILE block tile, BK=32, 4 waves (2x2), FM x FM frags of 16x16x32 MFMA.
// XCD-aware swizzle. EPI: 1 = silu + bf16, 5 = plain bf16 store,
// 6 = +embrow[t[m]][n] (bf16 table, LDS-gathered via batched glds16) + relu + bf16
//     (TILE==128 only),
// 4 = fused loss: acc -> LDS scoreboard -> per-(row,cat) loss (no store).
template <int EPI, int TILE>
__global__ __launch_bounds__(256) void gemm_mfma(
    const __hip_bfloat16* __restrict__ A, const __hip_bfloat16* __restrict__ Bt,
    const float* __restrict__ bias, void* __restrict__ Cout,
    int M, int Kd, int Nreal, int Cstride,
    const int* __restrict__ tidx, const float* __restrict__ rowbias,
    const int* __restrict__ x_cat, const int* __restrict__ t_in,
    const int* __restrict__ hot, const float* __restrict__ noise,
    const float* __restrict__ sched, double* __restrict__ acc_out) {
    constexpr int FM  = TILE / 32;   // MFMA frags per wave per dim
    constexpr int CPM = TILE / 16;   // 16-row staging chunks per matrix
    constexpr int CPW = TILE / 32;   // staging chunks per wave
    constexpr int STAGE = 4 * TILE * 32;  // As+Bs bytes
    constexpr int SCORE = TILE * TILE * 4;
    constexpr int SMEM_BYTES = (EPI == 4) ? (SCORE > STAGE ? SCORE : STAGE)
                               : (EPI == 6) ? (STAGE + TILE * TILE * 2)
                               : STAGE;
    __shared__ __align__(16) char SMEM[SMEM_BYTES];
    __hip_bfloat16* As = (__hip_bfloat16*)SMEM;
    __hip_bfloat16* Bs = As + TILE * 32;

    const int tid = threadIdx.x;
    const int lane = tid & 63, wave = tid >> 6;
    const int wm = wave >> 1, wn = wave & 1;

    // XCD swizzle (same-m n-blocks consecutive within one XCD)
    int mb, nb;
    {
        int nbx = gridDim.x, nby = gridDim.y;
        int b = blockIdx.y * nbx + blockIdx.x;
        if ((nby & 7) == 0) {
            int x = b & 7, g = b >> 3;
            nb = g % nbx;
            mb = x + 8 * (g / nbx);
        } else { mb = blockIdx.y; nb = blockIdx.x; }
    }
    const int m0 = mb * TILE, n0 = nb * TILE;

    const __hip_bfloat16* gsrc[CPW];
    char* ldst[CPW];
#pragma unroll
    for (int ii = 0; ii < CPW; ++ii) {
        int gc = wave * CPW + ii;
        int mat = gc / CPM, rem = gc % CPM;
        int row = rem * 16 + (lane >> 2);
        int col = (lane & 3) * 8;
        if (mat == 0) {
            int r = m0 + row; if (r > M - 1) r = M - 1;   // clamp; stores guarded
            gsrc[ii] = A + (size_t)r * Kd + col;
            ldst[ii] = (char*)As + rem * 1024;
        } else {
            int r = n0 + row;                             // Bt padded to tile
            gsrc[ii] = Bt + (size_t)r * Kd + col;
            ldst[ii] = (char*)Bs + rem * 1024;
        }
    }

    // EPI==6 (TILE==128): gather the block's 128 rowbias rows (bf16, 256 B each)
    // into LDS. ONE vector load of 32 t-values per wave, then 8 glds16 where
    // lane-group (lane>>4) covers row b*4+(lane>>4): per-lane global address
    // (shfl'd row id + (lane&15)*16B), wave-uniform LDS base (HW adds lane*16).
    // All 8 issue back-to-back; the K-loop's first barrier drains them.
    if (EPI == 6) {
        char* LE = SMEM + STAGE;
        const __hip_bfloat16* embp = (const __hip_bfloat16*)rowbias;
        int tvec = tidx[m0 + wave * 32 + (lane & 31)];
#pragma unroll
        for (int b = 0; b < 8; ++b) {
            int trow = __shfl(tvec, b * 4 + (lane >> 4));
            glds16((const char*)(embp + (size_t)trow * 1024 + n0) + (lane & 15) * 16,
                   LE + (wave * 32 + b * 4) * 256);
        }
    }

    f32x4 acc[FM][FM] = {};
    const int q8 = (lane >> 4) * 8;
    const int l15 = lane & 15;

    for (int k0 = 0; k0 < Kd; k0 += 32) {
#pragma unroll
        for (int ii = 0; ii < CPW; ++ii) glds16(gsrc[ii] + k0, ldst[ii]);
        __syncthreads();
        short8 af[FM], bfr[FM];
#pragma unroll
        for (int i = 0; i < FM; ++i) {
            af[i]  = *(const short8*)(As + (size_t)(wm * (TILE / 2) + i * 16 + l15) * 32 + q8);
            bfr[i] = *(const short8*)(Bs + (size_t)(wn * (TILE / 2) + i * 16 + l15) * 32 + q8);
        }
#pragma unroll
        for (int i = 0; i < FM; ++i)
#pragma unroll
            for (int j = 0; j < FM; ++j)
                acc[i][j] = __builtin_amdgcn_mfma_f32_16x16x32_bf16(
                    af[i], bfr[j], acc[i][j], 0, 0, 0);
        __syncthreads();
    }

    if (EPI == 4) {
        // Phase 1: dump raw acc to LDS scoreboard S[TILE][TILE] (f32, swizzled
        // col' = (col+row)&(TILE-1)). acc dies here -> no spill in K-loop.
        float* S = (float*)SMEM;
#pragma unroll
        for (int i = 0; i < FM; ++i) {
            int rbase = wm * (TILE / 2) + i * 16 + (lane >> 4) * 4;
#pragma unroll
            for (int j = 0; j < FM; ++j) {
                int lcol = wn * (TILE / 2) + j * 16 + l15;
#pragma unroll
                for (int r = 0; r < 4; ++r) {
                    int row = rbase + r;
                    S[row * TILE + ((lcol + row) & (TILE - 1))] = acc[i][j][r];
                }
            }
        }
        __syncthreads();

        // Phase 2: one (row, 16-col-group) pair per thread-iteration.
        double local = 0.0;
        const float* LOG_A = sched;
        const float* LOG_1M_A = sched + 1000;
        const float* LOG_CA = sched + 2000;
        const float* LOG_1M_CA = sched + 3000;
        constexpr int PAIRS = TILE * (TILE / 16);
        for (int p = tid; p < PAIRS; p += 256) {
            int ml = p & (TILE - 1), cg = p / TILE;
            int colbase = n0 + cg * 16;
            if (colbase >= 400) continue;     // zero-pad cols
            int m = m0 + ml;
            float ocv[16];
#pragma unroll
            for (int k = 0; k < 16; ++k)
                ocv[k] = S[ml * TILE + ((cg * 16 + k + ml) & (TILE - 1))] + bias[colbase + k];
            if (colbase == 0) {
                // gaussian block
#pragma unroll
                for (int k = 0; k < 16; ++k) {
                    float d = noise[(size_t)m * 16 + k] - ocv[k];
                    local += (double)(d * d) * (1.0 / (16.0 * BATCH));
                }
            } else {
                int c = (colbase - 16) >> 4;
                int t = t_in[m];
                int xc = x_cat[m * 24 + c];
                int s = hot[m * 24 + c];
                float mx = -3e38f;
#pragma unroll
                for (int k = 0; k < 16; ++k) mx = fmaxf(mx, ocv[k]);
                float sm = 0.0f;
#pragma unroll
                for (int k = 0; k < 16; ++k) sm += expf(ocv[k] - mx);
                float lse = mx + logf(sm);
                int tm1 = (t > 0) ? t - 1 : 0;
                float lca1 = LOG_CA[tm1];
                float l1m1 = LOG_1M_CA[tm1] - LOGKF;
                float la = LOG_A[t];
                float l1a = LOG_1M_A[t] - LOGKF;
                float qh = lae(la, l1a);
                float qo = lae(L30F + la, l1a);
                float levh = (t == 0) ? 0.0f : lae(lca1, l1m1);
                float levo = (t == 0) ? L30F : lae(L30F + lca1, l1m1);
                float un[16], ut[16];
                float mu = -3e38f, mt2 = -3e38f;
#pragma unroll
                for (int k = 0; k < 16; ++k) {
                    float lxh = ocv[k] - lse;
                    float lev = (t == 0) ? lxh : lae(lxh + lca1, l1m1);
                    float q = (k == s) ? qh : qo;
                    un[k] = lev + q;
                    ut[k] = ((k == xc) ? levh : levo) + q;
                    mu = fmaxf(mu, un[k]);
                    mt2 = fmaxf(mt2, ut[k]);
                }
                float su = 0.0f, st = 0.0f;
#pragma unroll
                for (int k = 0; k < 16; ++k) { su += expf(un[k] - mu); st += expf(ut[k] - mt2); }
                float lsu = mu + logf(su), lst = mt2 + logf(st);
                float kl = 0.0f, dn = 0.0f;
#pragma unroll
                for (int k = 0; k < 16; ++k) {
                    float lmp = un[k] - lsu;
                    float ltp = ut[k] - lst;
                    kl += expf(ltp) * (ltp - lmp);
                    dn -= ((k == xc) ? 1.0f : 1e-30f) * lmp;
                }
                float Lt = (t == 0) ? dn : kl;
                local += (double)Lt * (1.0 / (24.0 * BATCH));
            }
        }
        // block reduction (wred aliases S after sync)
        for (int off = 32; off > 0; off >>= 1)
            local += __shfl_down(local, off);
        __syncthreads();
        double* wred = (double*)SMEM;
        if (lane == 0) wred[wave] = local;
        __syncthreads();
        if (tid == 0)
            atomicAdd(acc_out, wred[0] + wred[1] + wred[2] + wred[3]);
        return;
    }

    const __hip_bfloat16* LE = (const __hip_bfloat16*)(SMEM + STAGE);
#pragma unroll
    for (int i = 0; i < FM; ++i) {
        int mlbase = wm * (TILE / 2) + i * 16 + (lane >> 4) * 4;
#pragma unroll
        for (int j = 0; j < FM; ++j) {
            int nl = wn * (TILE / 2) + j * 16 + l15;
            int n = n0 + nl;
            if (n >= Nreal) continue;
            float bv = bias[n];
#pragma unroll
            for (int r = 0; r < 4; ++r) {
                int ml = mlbase + r;
                int m = m0 + ml;
                if (m >= M) continue;
                float v = acc[i][j][r] + bv;
                if (EPI == 1) v = v / (1.0f + expf(-v));
                if (EPI == 6) { v += __bfloat162float(LE[ml * TILE + nl]); v = fmaxf(v, 0.0f); }
                ((__hip_bfloat16*)Cout)[(size_t)m * Cstride + n] = __float2bfloat16(v);
            }
        }
    }
}

// ----------------------- per-row prep: gumbel argmax + build X[B x 416] bf16
// X = [x_num_t (16) | delta-onehot*69.0776 (384) | zeros (16)]
__global__ __launch_bounds__(256) void prep_x(
    const float* __restrict__ x_num, const int* __restrict__ x_cat,
    const int* __restrict__ t_in, const float* __restrict__ noise,
    const float* __restrict__ gum, const float* __restrict__ sched,
    __hip_bfloat16* __restrict__ X, int* __restrict__ hot) {
    __shared__ float xnt[16][16];
    __shared__ int sh_hot[16][24];
    __shared__ int sh_t[16];
    const int b0 = blockIdx.x * 16;
    const int tid = threadIdx.x;
    const float* LOG_CA = sched + 2000;
    const float* LOG_1M_CA = sched + 3000;
    const float* SQ_AC = sched + 4000;
    const float* SQ_1M = sched + 5000;
    if (tid < 16) sh_t[tid] = t_in[b0 + tid];
    __syncthreads();
    {
        int r = tid >> 4, i = tid & 15;
        int t = sh_t[r];
        xnt[r][i] = SQ_AC[t] * x_num[(size_t)(b0 + r) * 16 + i] +
                    SQ_1M[t] * noise[(size_t)(b0 + r) * 16 + i];
    }
    for (int task = tid; task < 16 * 24; task += 256) {
        int r = task / 24, c = task - r * 24;
        int t = sh_t[r];
        int xc = x_cat[(size_t)(b0 + r) * 24 + c];
        float l1 = LOG_1M_CA[t] - LOGKF;
        float lca = LOG_CA[t];
        float vh = lae(lca, l1);
        float vo = lae(L30F + lca, l1);
        const float* gu = gum + (size_t)(b0 + r) * 384 + c * 16;
        float best = -3.0e38f;
        int bi = 0;
#pragma unroll
        for (int k = 0; k < 16; ++k) {
            float g = -logf(-logf(gu[k] + 1e-30f) + 1e-30f);
            float v = g + ((k == xc) ? vh : vo);
            if (v > best) { best = v; bi = k; }
        }
        sh_hot[r][c] = bi;
        hot[(size_t)(b0 + r) * 24 + c] = bi;
    }
    __syncthreads();
    const float DELTA = 69.07755279f;  // -L30F
#pragma unroll
    for (int it = 0; it < 4; ++it) {
        int idx = it * 256 + tid;          // need 16*52 = 832 short8 stores
        if (idx < 832) {
            int r = idx / 52, jc = idx - r * 52;
            int j0 = jc * 8;
            __hip_bfloat16 v[8];
#pragma unroll
            for (int qq = 0; qq < 8; ++qq) {
                int j = j0 + qq;
                float f = 0.0f;
                if (j < 16) {
                    f = xnt[r][j];
                } else if (j < 400) {
                    int c = (j - 16) >> 4, k = (j - 16) & 15;
                    f = (sh_hot[r][c] == k) ? DELTA : 0.0f;
                }
                v[qq] = __float2bfloat16(f);
            }
            *(short8*)(X + (size_t)(b0 + r) * 416 + j0) = *(const short8*)v;
        }
    }
}

__global__ void finalize_kernel(const double* __restrict__ acc,
                                const float* __restrict__ sched,
                                float* __restrict__ out) {
    // kl_prior is identical for every (sample, category): add once.
    float lcaT = sched[2999];
    float l1mT = sched[3999] - LOGKF;
    float ph = lae(lcaT, l1mT);
    float po = lae(L30F + lcaT, l1mT);
    float prior = expf(ph) * (ph + LOGKF) + 15.0f * expf(po) * (po + LOGKF);
    out[0] = (float)(*acc + (double)prior);
}

extern "C" void kernel_launch(void* const* d_in, const int* in_sizes, int n_in,
                              void* d_out, int out_size, void* d_ws, size_t ws_size,
                              hipStream_t stream) {
    const float* x_num  = (const float*)d_in[0];
    const int*   x_cat  = (const int*)d_in[1];
    const int*   t_in   = (const int*)d_in[2];
    const float* noise  = (const float*)d_in[3];
    const float* gum    = (const float*)d_in[4];
    const float* te_w1  = (const float*)d_in[5];
    const float* te_b1  = (const float*)d_in[6];
    const float* te_w2  = (const float*)d_in[7];
    const float* te_b2  = (const float*)d_in[8];
    const float* proj_w = (const float*)d_in[9];
    const float* proj_b = (const float*)d_in[10];
    const float* mlp_w1 = (const float*)d_in[11];
    const float* mlp_b1 = (const float*)d_in[12];
    const float* mlp_w2 = (const float*)d_in[13];
    const float* mlp_b2 = (const float*)d_in[14];
    float* out = (float*)d_out;

    char* w = (char*)d_ws;
    size_t off = 0;
    auto alloc = [&](size_t bytes) {
        void* p = w + off;
        off += (bytes + 1023) & ~(size_t)1023;
        return p;
    };
    double* acc     = (double*)alloc(1024);
    float* sched    = (float*)alloc(6 * 1000 * 4);
    int*   hot      = (int*)alloc((size_t)BATCH * 24 * 4);
    float* colconst = (float*)alloc(1024 * 4);
    float* zbias    = (float*)alloc(1024 * 4);
    __hip_bfloat16* E0    = (__hip_bfloat16*)alloc((size_t)1024 * 1024 * 2);
    __hip_bfloat16* E1    = (__hip_bfloat16*)alloc((size_t)1024 * 1024 * 2);
    __hip_bfloat16* EMBp  = (__hip_bfloat16*)alloc((size_t)1024 * 1024 * 2);
    __hip_bfloat16* EMB2  = (__hip_bfloat16*)alloc((size_t)1024 * 1024 * 2);
    __hip_bfloat16* tw1t  = (__hip_bfloat16*)alloc((size_t)1024 * 1024 * 2);
    __hip_bfloat16* tw2t  = (__hip_bfloat16*)alloc((size_t)1024 * 1024 * 2);
    __hip_bfloat16* w1t   = (__hip_bfloat16*)alloc((size_t)1024 * 1024 * 2);
    __hip_bfloat16* w2t   = (__hip_bfloat16*)alloc((size_t)512 * 1024 * 2);
    __hip_bfloat16* pjb   = (__hip_bfloat16*)alloc((size_t)448 * 1024 * 2);
    __hip_bfloat16* PWT   = (__hip_bfloat16*)alloc((size_t)1024 * 416 * 2);
    __hip_bfloat16* X     = (__hip_bfloat16*)alloc((size_t)BATCH * 416 * 2);
    __hip_bfloat16* R     = (__hip_bfloat16*)alloc((size_t)BATCH * 1024 * 2);

    // setup: 4 transposes + pjb cast + E0 table + colconst/zbias + schedules
    setup_all<<<7813, 256, 0, stream>>>(te_w1, te_w2, mlp_w1, mlp_w2,
                                        tw1t, tw2t, w1t, w2t, pjb,
                                        E0, proj_w, proj_b, te_b2,
                                        colconst, zbias, sched, acc);
    // X + hot
    prep_x<<<BATCH / 16, 256, 0, stream>>>(x_num, x_cat, t_in, noise, gum, sched, X, hot);
    // PWT[j,k] = sum_n w1[n,j] proj_w[k,n]  -> [1024 x 416] bf16
    gemm_mfma<5, 64><<<dim3(7, 16), 256, 0, stream>>>(
        w1t, pjb, zbias, PWT, 1024, 1024, 416, 416,
        nullptr, nullptr, nullptr, nullptr, nullptr, nullptr, nullptr, nullptr);
    // E1 = silu(E0 @ te_w1 + te_b1)
    gemm_mfma<1, 64><<<dim3(16, 16), 256, 0, stream>>>(
        E0, tw1t, te_b1, E1, 1000, 1024, 1024, 1024,
        nullptr, nullptr, nullptr, nullptr, nullptr, nullptr, nullptr, nullptr);
    // EMBp = E1 @ te_w2 + (te_b2 + proj_b + L30F*catsum)   [all h-space consts]
    gemm_mfma<5, 64><<<dim3(16, 16), 256, 0, stream>>>(
        E1, tw2t, colconst, EMBp, 1000, 1024, 1024, 1024,
        nullptr, nullptr, nullptr, nullptr, nullptr, nullptr, nullptr, nullptr);
    // EMB2 = EMBp @ w1 + b1   [per-t hidden-layer bias table]
    gemm_mfma<5, 64><<<dim3(16, 16), 256, 0, stream>>>(
        EMBp, w1t, mlp_b1, EMB2, 1000, 1024, 1024, 1024,
        nullptr, nullptr, nullptr, nullptr, nullptr, nullptr, nullptr, nullptr);
    // R = relu(X @ PWT^T + EMB2[t])   [h-GEMM + R-GEMM collapsed; batched gather]
    gemm_mfma<6, 128><<<dim3(8, 128), 256, 0, stream>>>(
        X, PWT, zbias, R, BATCH, 416, 1024, 1024,
        t_in, (const float*)EMB2, nullptr, nullptr, nullptr, nullptr, nullptr, nullptr);
    // fused: (R @ mlp_w2 + mlp_b2) -> LDS scoreboard -> loss (TILE=64, no store)
    gemm_mfma<4, 64><<<dim3(7, 256), 256, 0, stream>>>(
        R, w2t, mlp_b2, nullptr, BATCH, 1024, 400, 0,
        nullptr, nullptr, x_cat, t_in, hot, noise, sched, acc);
    finalize_kernel<<<1, 1, 0, stream>>>(acc, sched, out);
}

// Round 11
// 305.061 us; speedup vs baseline: 1.4888x; 1.0018x over previous
//
#include <hip/hip_runtime.h>
#include <hip/hip_bf16.h>
#include <math.h>

#define BATCH 16384
#define NCAT 24

// log(1e-30f), log(16)
#define L30F  (-69.07755279f)
#define LOGKF (2.7725887f)

typedef __attribute__((ext_vector_type(8))) short short8;
typedef __attribute__((ext_vector_type(4))) float f32x4;

__device__ __forceinline__ float lae(float a, float b) {
    float m = fmaxf(a, b);
    return m + logf(expf(a - m) + expf(b - m));
}

__device__ __forceinline__ void glds16(const void* g, void* l) {
    __builtin_amdgcn_global_load_lds((const __attribute__((address_space(1))) void*)g,
                                     (__attribute__((address_space(3))) void*)l,
                                     16, 0, 0);
}

// --- fused setup: 4x weight transpose + proj_w bf16 cast + E0 + colconst + sched
// blocks [0,3584): transposes {te_w1,te_w2,mlp_w1,mlp_w2} -> bf16 [Npad x 1024]
// blocks [3584,3808): pjb = bf16(proj_w) [448 x 1024], rows >= 400 zero
// blocks [3808,7808): E0 bf16 timestep-embedding table (1000x1024)
// blocks [7808,7812): colconst[j] = te_b2[j]+proj_b[j]+L30F*sum proj_w[16:400][j]; zbias=0
// block 7812: schedules + per-t loss table + acc zero
__global__ __launch_bounds__(256) void setup_all(
    const float* __restrict__ s0, const float* __restrict__ s1,
    const float* __restrict__ s2, const float* __restrict__ s3,
    __hip_bfloat16* __restrict__ d0, __hip_bfloat16* __restrict__ d1,
    __hip_bfloat16* __restrict__ d2, __hip_bfloat16* __restrict__ d3,
    __hip_bfloat16* __restrict__ pjb,
    __hip_bfloat16* __restrict__ E0, const float* __restrict__ proj_w,
    const float* __restrict__ proj_b, const float* __restrict__ te_b2,
    float* __restrict__ colconst, float* __restrict__ zbias,
    float* __restrict__ sched, float* __restrict__ ltbl,
    double* __restrict__ acc) {
    const int bid = blockIdx.x, tid = threadIdx.x;
    if (bid < 3584) {
        // transpose: W[K x Nw] f32 -> Wt[Npad x 1024] bf16 (zero pad)
        const int boff[5] = {0, 1024, 2048, 3072, 3584};
        const int nxs[4]  = {32, 32, 32, 16};
        const int Nws[4]  = {1024, 1024, 1024, 400};
        const int Nps[4]  = {1024, 1024, 1024, 512};
        int job = 0;
#pragma unroll
        for (int j = 1; j < 4; ++j) job += (bid >= boff[j]) ? 1 : 0;
        const float* W = (job == 0) ? s0 : (job == 1) ? s1 : (job == 2) ? s2 : s3;
        __hip_bfloat16* Wt = (job == 0) ? d0 : (job == 1) ? d1 : (job == 2) ? d2 : d3;
        const int lb = bid - boff[job];
        const int Nw = Nws[job], Npad = Nps[job];
        const int n0 = (lb % nxs[job]) * 32, k0 = (lb / nxs[job]) * 32;
        __shared__ float t[32][33];
        int c = tid & 31, r8 = tid >> 5;
#pragma unroll
        for (int i = 0; i < 32; i += 8) {
            int k = k0 + r8 + i, n = n0 + c;
            t[r8 + i][c] = (n < Nw) ? W[(size_t)k * Nw + n] : 0.0f;
        }
        __syncthreads();
#pragma unroll
        for (int i = 0; i < 32; i += 8) {
            int n = n0 + r8 + i, k = k0 + c;
            if (n < Npad) Wt[(size_t)n * 1024 + k] = __float2bfloat16(t[c][r8 + i]);
        }
    } else if (bid < 3808) {
        int idx = (bid - 3584) * 2048 + tid * 8;
        int r = idx >> 10;
        __hip_bfloat16 v[8];
        if (r < 400) {
            const float* src = proj_w + idx;
#pragma unroll
            for (int q = 0; q < 8; ++q) v[q] = __float2bfloat16(src[q]);
        } else {
#pragma unroll
            for (int q = 0; q < 8; ++q) v[q] = __float2bfloat16(0.0f);
        }
        *(short8*)(pjb + idx) = *(const short8*)v;
    } else if (bid < 7808) {
        int gid = (bid - 3808) * 256 + tid;
        int t = gid >> 10, j = gid & 1023;
        int jj = (j < 512) ? j : j - 512;
        float freq = expf(-logf(10000.0f) * (float)jj / 512.0f);
        float arg = (float)t * freq;
        E0[gid] = __float2bfloat16((j < 512) ? cosf(arg) : sinf(arg));
    } else if (bid < 7812) {
        int j = (bid - 7808) * 256 + tid;
        float s = 0.0f;
        for (int r = 16; r < 400; ++r) s += proj_w[(size_t)r * 1024 + j];
        colconst[j] = te_b2[j] + proj_b[j] + L30F * s;
        zbias[j] = 0.0f;
    } else {
        __shared__ double la_s[1000];
        __shared__ double lca_s[1000];
        const double PI = 3.14159265358979323846;
        for (int i = tid; i < 1000; i += 256) {
            double u0 = ((double)i / 1000.0 + 0.008) / 1.008 * PI * 0.5;
            double u1 = ((double)(i + 1) / 1000.0 + 0.008) / 1.008 * PI * 0.5;
            double c0 = cos(u0), c1 = cos(u1);
            double beta = 1.0 - (c1 * c1) / (c0 * c0);
            if (beta > 0.999) beta = 0.999;
            la_s[i] = log(1.0 - beta);
        }
        __syncthreads();
        if (tid == 0) {
            double run = 0.0;
            for (int i = 0; i < 1000; ++i) { run += la_s[i]; lca_s[i] = run; }
            *acc = 0.0;
        }
        __syncthreads();
        for (int i = tid; i < 1000; i += 256) {
            double la = la_s[i], lca = lca_s[i];
            sched[i]        = (float)la;
            sched[1000 + i] = (float)log(1.0 - exp(la) + 1e-40);
            sched[2000 + i] = (float)lca;
            sched[3000 + i] = (float)log(1.0 - exp(lca) + 1e-40);
            sched[4000 + i] = (float)sqrt(exp(lca));
            sched[5000 + i] = (float)sqrt(1.0 - exp(lca));
            // per-t loss table: {A1, B1, B1p, Qh, Qo, C0 (xc!=s), C1 (xc==s), 0}
            double alpha = exp(la);
            double A1, B1;
            if (i == 0) { A1 = 1.0; B1 = 0.0; }
            else { double ab = exp(lca_s[i - 1]); A1 = ab; B1 = (1.0 - ab) / 16.0; }
            double B1p = 1e-30 * A1 + B1;
            double Qh = alpha + (1.0 - alpha) / 16.0;
            double Qo = 1e-30 * alpha + (1.0 - alpha) / 16.0;
            double C0 = 0.0, C1 = 0.0;
            if (i > 0) {
                double UTh1 = (A1 + B1) * Qh, UTo = B1p * Qo, UTs = B1p * Qh;
                double ST1 = UTh1 + 15.0 * UTo;
                double p1 = UTh1 / ST1, p0 = UTo / ST1;
                C1 = p1 * log(p1) + 15.0 * p0 * log(p0);
                double UTh0 = (A1 + B1) * Qo;
                double ST0 = UTh0 + UTs + 14.0 * UTo;
                double pxc = UTh0 / ST0, ps = UTs / ST0, po = UTo / ST0;
                C0 = pxc * log(pxc) + ps * log(ps) + 14.0 * po * log(po);
            }
            ltbl[i * 8 + 0] = (float)A1;
            ltbl[i * 8 + 1] = (float)B1;
            ltbl[i * 8 + 2] = (float)B1p;
            ltbl[i * 8 + 3] = (float)Qh;
            ltbl[i * 8 + 4] = (float)Qo;
            ltbl[i * 8 + 5] = (float)C0;
            ltbl[i * 8 + 6] = (float)C1;
            ltbl[i * 8 + 7] = 0.0f;
        }
    }
}

// ------------------------------------------------------------ bf16 MFMA GEMM
// C[M,Nreal] = epi(A[M,Kd] @ Bt^T + bias), A row-major bf16, Bt [Npad x Kd] bf16.
// TILE x TILE block tile, BK=32, 4 waves (2x2), FM x FM frags of 16x16x32 MFMA.
// XCD-aware swizzle. EPI: 1 = silu + bf16, 5 = plain bf16 store,
// 6 = +embrow[t[m]][n] (bf16 table, LDS-gathered via batched glds16) + relu + bf16
//     (TILE==128 only),
// 4 = fused loss: acc -> LDS scoreboard -> per-(row,cat) linear-space loss
//     (rowbias carries the per-t loss table; no store).
template <int EPI, int TILE>
__global__ __launch_bounds__(256) void gemm_mfma(
    const __hip_bfloat16* __restrict__ A, const __hip_bfloat16* __restrict__ Bt,
    const float* __restrict__ bias, void* __restrict__ Cout,
    int M, int Kd, int Nreal, int Cstride,
    const int* __restrict__ tidx, const float* __restrict__ rowbias,
    const int* __restrict__ x_cat, const int* __restrict__ t_in,
    const int* __restrict__ hot, const float* __restrict__ noise,
    const float* __restrict__ sched, double* __restrict__ acc_out) {
    constexpr int FM  = TILE / 32;   // MFMA frags per wave per dim
    constexpr int CPM = TILE / 16;   // 16-row staging chunks per matrix
    constexpr int CPW = TILE / 32;   // staging chunks per wave
    constexpr int STAGE = 4 * TILE * 32;  // As+Bs bytes
    constexpr int SCORE = TILE * TILE * 4;
    constexpr int SMEM_BYTES = (EPI == 4) ? (SCORE > STAGE ? SCORE : STAGE)
                               : (EPI == 6) ? (STAGE + TILE * TILE * 2)
                               : STAGE;
    __shared__ __align__(16) char SMEM[SMEM_BYTES];
    __hip_bfloat16* As = (__hip_bfloat16*)SMEM;
    __hip_bfloat16* Bs = As + TILE * 32;

    const int tid = threadIdx.x;
    const int lane = tid & 63, wave = tid >> 6;
    const int wm = wave >> 1, wn = wave & 1;

    // XCD swizzle (same-m n-blocks consecutive within one XCD)
    int mb, nb;
    {
        int nbx = gridDim.x, nby = gridDim.y;
        int b = blockIdx.y * nbx + blockIdx.x;
        if ((nby & 7) == 0) {
            int x = b & 7, g = b >> 3;
            nb = g % nbx;
            mb = x + 8 * (g / nbx);
        } else { mb = blockIdx.y; nb = blockIdx.x; }
    }
    const int m0 = mb * TILE, n0 = nb * TILE;

    const __hip_bfloat16* gsrc[CPW];
    char* ldst[CPW];
#pragma unroll
    for (int ii = 0; ii < CPW; ++ii) {
        int gc = wave * CPW + ii;
        int mat = gc / CPM, rem = gc % CPM;
        int row = rem * 16 + (lane >> 2);
        int col = (lane & 3) * 8;
        if (mat == 0) {
            int r = m0 + row; if (r > M - 1) r = M - 1;   // clamp; stores guarded
            gsrc[ii] = A + (size_t)r * Kd + col;
            ldst[ii] = (char*)As + rem * 1024;
        } else {
            int r = n0 + row;                             // Bt padded to tile
            gsrc[ii] = Bt + (size_t)r * Kd + col;
            ldst[ii] = (char*)Bs + rem * 1024;
        }
    }

    // EPI==6 (TILE==128): gather the block's 128 rowbias rows (bf16, 256 B each)
    // into LDS via batched glds16 (per-lane global addr, wave-uniform LDS base).
    if (EPI == 6) {
        char* LE = SMEM + STAGE;
        const __hip_bfloat16* embp = (const __hip_bfloat16*)rowbias;
        int tvec = tidx[m0 + wave * 32 + (lane & 31)];
#pragma unroll
        for (int b = 0; b < 8; ++b) {
            int trow = __shfl(tvec, b * 4 + (lane >> 4));
            glds16((const char*)(embp + (size_t)trow * 1024 + n0) + (lane & 15) * 16,
                   LE + (wave * 32 + b * 4) * 256);
        }
    }

    f32x4 acc[FM][FM] = {};
    const int q8 = (lane >> 4) * 8;
    const int l15 = lane & 15;

    for (int k0 = 0; k0 < Kd; k0 += 32) {
#pragma unroll
        for (int ii = 0; ii < CPW; ++ii) glds16(gsrc[ii] + k0, ldst[ii]);
        __syncthreads();
        short8 af[FM], bfr[FM];
#pragma unroll
        for (int i = 0; i < FM; ++i) {
            af[i]  = *(const short8*)(As + (size_t)(wm * (TILE / 2) + i * 16 + l15) * 32 + q8);
            bfr[i] = *(const short8*)(Bs + (size_t)(wn * (TILE / 2) + i * 16 + l15) * 32 + q8);
        }
#pragma unroll
        for (int i = 0; i < FM; ++i)
#pragma unroll
            for (int j = 0; j < FM; ++j)
                acc[i][j] = __builtin_amdgcn_mfma_f32_16x16x32_bf16(
                    af[i], bfr[j], acc[i][j], 0, 0, 0);
        __syncthreads();
    }

    if (EPI == 4) {
        // Phase 1: dump raw acc to LDS scoreboard S[TILE][TILE] (f32, swizzled
        // col' = (col+row)&(TILE-1)). acc dies here -> no spill in K-loop.
        float* S = (float*)SMEM;
#pragma unroll
        for (int i = 0; i < FM; ++i) {
            int rbase = wm * (TILE / 2) + i * 16 + (lane >> 4) * 4;
#pragma unroll
            for (int j = 0; j < FM; ++j) {
                int lcol = wn * (TILE / 2) + j * 16 + l15;
#pragma unroll
                for (int r = 0; r < 4; ++r) {
                    int row = rbase + r;
                    S[row * TILE + ((lcol + row) & (TILE - 1))] = acc[i][j][r];
                }
            }
        }
        __syncthreads();

        // Phase 2: one (row, 16-col-group) pair per thread. Linear-space loss:
        // kl = C - sum_k W[k]*(log U[k] - log SU) with per-t table constants.
        double local = 0.0;
        const float* ltbl = rowbias;
        constexpr int PAIRS = TILE * (TILE / 16);
        for (int p = tid; p < PAIRS; p += 256) {
            int ml = p & (TILE - 1), cg = p / TILE;
            int colbase = n0 + cg * 16;
            if (colbase >= 400) continue;     // zero-pad cols
            int m = m0 + ml;
            float ocv[16];
#pragma unroll
            for (int k = 0; k < 16; ++k)
                ocv[k] = S[ml * TILE + ((cg * 16 + k + ml) & (TILE - 1))] + bias[colbase + k];
            if (colbase == 0) {
                // gaussian block
#pragma unroll
                for (int k = 0; k < 16; ++k) {
                    float d = noise[(size_t)m * 16 + k] - ocv[k];
                    local += (double)(d * d) * (1.0 / (16.0 * BATCH));
                }
            } else {
                int c = (colbase - 16) >> 4;
                int t = t_in[m];
                int xc = x_cat[m * 24 + c];
                int s = hot[m * 24 + c];
                const float* tb = ltbl + t * 8;
                float A1 = tb[0], B1 = tb[1], B1p = tb[2], Qh = tb[3], Qo = tb[4];
                float mx = -3e38f;
#pragma unroll
                for (int k = 0; k < 16; ++k) mx = fmaxf(mx, ocv[k]);
                float E[16];
                float sm = 0.0f;
#pragma unroll
                for (int k = 0; k < 16; ++k) { E[k] = expf(ocv[k] - mx); sm += E[k]; }
                float A1s = A1 / sm;
                float SU = 0.0f, slU = 0.0f, lUxc = 0.0f, lUs = 0.0f;
#pragma unroll
                for (int k = 0; k < 16; ++k) {
                    float U = (E[k] * A1s + B1) * ((k == s) ? Qh : Qo);
                    SU += U;
                    float l = logf(fmaxf(U, 1e-37f));
                    slU += l;
                    if (k == xc) lUxc = l;
                    if (k == s)  lUs = l;
                }
                float lSU = logf(SU);
                float Wh, Ws, Wo, C;
                if (t == 0) {
                    Wh = 1.0f; Ws = 1e-30f; Wo = 1e-30f; C = 0.0f;
                } else {
                    int e = (xc == s);
                    float UTh = (A1 + B1) * (e ? Qh : Qo);
                    float UTs = B1p * Qh;
                    float UTo = B1p * Qo;
                    float ST = e ? (UTh + 15.0f * UTo) : (UTh + UTs + 14.0f * UTo);
                    float rST = 1.0f / ST;
                    Wh = UTh * rST; Wo = UTo * rST; Ws = UTs * rST;
                    C = e ? tb[6] : tb[5];
                }
                float wsTerm = (xc == s) ? 0.0f : (Ws - Wo);
                float SPU = Wo * slU + (Wh - Wo) * lUxc + wsTerm * lUs;
                float Lt = C - SPU + lSU;
                local += (double)Lt * (1.0 / (24.0 * BATCH));
            }
        }
        // block reduction (wred aliases S after sync)
        for (int off = 32; off > 0; off >>= 1)
            local += __shfl_down(local, off);
        __syncthreads();
        double* wred = (double*)SMEM;
        if (lane == 0) wred[wave] = local;
        __syncthreads();
        if (tid == 0)
            atomicAdd(acc_out, wred[0] + wred[1] + wred[2] + wred[3]);
        return;
    }

    const __hip_bfloat16* LE = (const __hip_bfloat16*)(SMEM + STAGE);
#pragma unroll
    for (int i = 0; i < FM; ++i) {
        int mlbase = wm * (TILE / 2) + i * 16 + (lane >> 4) * 4;
#pragma unroll
        for (int j = 0; j < FM; ++j) {
            int nl = wn * (TILE / 2) + j * 16 + l15;
            int n = n0 + nl;
            if (n >= Nreal) continue;
            float bv = bias[n];
#pragma unroll
            for (int r = 0; r < 4; ++r) {
                int ml = mlbase + r;
                int m = m0 + ml;
                if (m >= M) continue;
                float v = acc[i][j][r] + bv;
                if (EPI == 1) v = v / (1.0f + expf(-v));
                if (EPI == 6) { v += __bfloat162float(LE[ml * TILE + nl]); v = fmaxf(v, 0.0f); }
                ((__hip_bfloat16*)Cout)[(size_t)m * Cstride + n] = __float2bfloat16(v);
            }
        }
    }
}

// ----------------------- per-row prep: gumbel argmax + build X[B x 416] bf16
// X = [x_num_t (16) | delta-onehot*69.0776 (384) | zeros (16)]
__global__ __launch_bounds__(256) void prep_x(
    const float* __restrict__ x_num, const int* __restrict__ x_cat,
    const int* __restrict__ t_in, const float* __restrict__ noise,
    const float* __restrict__ gum, const float* __restrict__ sched,
    __hip_bfloat16* __restrict__ X, int* __restrict__ hot) {
    __shared__ float xnt[16][16];
    __shared__ int sh_hot[16][24];
    __shared__ int sh_t[16];
    const int b0 = blockIdx.x * 16;
    const int tid = threadIdx.x;
    const float* LOG_CA = sched + 2000;
    const float* LOG_1M_CA = sched + 3000;
    const float* SQ_AC = sched + 4000;
    const float* SQ_1M = sched + 5000;
    if (tid < 16) sh_t[tid] = t_in[b0 + tid];
    __syncthreads();
    {
        int r = tid >> 4, i = tid & 15;
        int t = sh_t[r];
        xnt[r][i] = SQ_AC[t] * x_num[(size_t)(b0 + r) * 16 + i] +
                    SQ_1M[t] * noise[(size_t)(b0 + r) * 16 + i];
    }
    for (int task = tid; task < 16 * 24; task += 256) {
        int r = task / 24, c = task - r * 24;
        int t = sh_t[r];
        int xc = x_cat[(size_t)(b0 + r) * 24 + c];
        float l1 = LOG_1M_CA[t] - LOGKF;
        float lca = LOG_CA[t];
        float vh = lae(lca, l1);
        float vo = lae(L30F + lca, l1);
        const float* gu = gum + (size_t)(b0 + r) * 384 + c * 16;
        float best = -3.0e38f;
        int bi = 0;
#pragma unroll
        for (int k = 0; k < 16; ++k) {
            float g = -logf(-logf(gu[k] + 1e-30f) + 1e-30f);
            float v = g + ((k == xc) ? vh : vo);
            if (v > best) { best = v; bi = k; }
        }
        sh_hot[r][c] = bi;
        hot[(size_t)(b0 + r) * 24 + c] = bi;
    }
    __syncthreads();
    const float DELTA = 69.07755279f;  // -L30F
#pragma unroll
    for (int it = 0; it < 4; ++it) {
        int idx = it * 256 + tid;          // need 16*52 = 832 short8 stores
        if (idx < 832) {
            int r = idx / 52, jc = idx - r * 52;
            int j0 = jc * 8;
            __hip_bfloat16 v[8];
#pragma unroll
            for (int qq = 0; qq < 8; ++qq) {
                int j = j0 + qq;
                float f = 0.0f;
                if (j < 16) {
                    f = xnt[r][j];
                } else if (j < 400) {
                    int c = (j - 16) >> 4, k = (j - 16) & 15;
                    f = (sh_hot[r][c] == k) ? DELTA : 0.0f;
                }
                v[qq] = __float2bfloat16(f);
            }
            *(short8*)(X + (size_t)(b0 + r) * 416 + j0) = *(const short8*)v;
        }
    }
}

__global__ void finalize_kernel(const double* __restrict__ acc,
                                const float* __restrict__ sched,
                                float* __restrict__ out) {
    // kl_prior is identical for every (sample, category): add once.
    float lcaT = sched[2999];
    float l1mT = sched[3999] - LOGKF;
    float ph = lae(lcaT, l1mT);
    float po = lae(L30F + lcaT, l1mT);
    float prior = expf(ph) * (ph + LOGKF) + 15.0f * expf(po) * (po + LOGKF);
    out[0] = (float)(*acc + (double)prior);
}

extern "C" void kernel_launch(void* const* d_in, const int* in_sizes, int n_in,
                              void* d_out, int out_size, void* d_ws, size_t ws_size,
                              hipStream_t stream) {
    const float* x_num  = (const float*)d_in[0];
    const int*   x_cat  = (const int*)d_in[1];
    const int*   t_in   = (const int*)d_in[2];
    const float* noise  = (const float*)d_in[3];
    const float* gum    = (const float*)d_in[4];
    const float* te_w1  = (const float*)d_in[5];
    const float* te_b1  = (const float*)d_in[6];
    const float* te_w2  = (const float*)d_in[7];
    const float* te_b2  = (const float*)d_in[8];
    const float* proj_w = (const float*)d_in[9];
    const float* proj_b = (const float*)d_in[10];
    const float* mlp_w1 = (const float*)d_in[11];
    const float* mlp_b1 = (const float*)d_in[12];
    const float* mlp_w2 = (const float*)d_in[13];
    const float* mlp_b2 = (const float*)d_in[14];
    float* out = (float*)d_out;

    char* w = (char*)d_ws;
    size_t off = 0;
    auto alloc = [&](size_t bytes) {
        void* p = w + off;
        off += (bytes + 1023) & ~(size_t)1023;
        return p;
    };
    double* acc     = (double*)alloc(1024);
    float* sched    = (float*)alloc(6 * 1000 * 4);
    float* ltbl     = (float*)alloc(8 * 1000 * 4);
    int*   hot      = (int*)alloc((size_t)BATCH * 24 * 4);
    float* colconst = (float*)alloc(1024 * 4);
    float* zbias    = (float*)alloc(1024 * 4);
    __hip_bfloat16* E0    = (__hip_bfloat16*)alloc((size_t)1024 * 1024 * 2);
    __hip_bfloat16* E1    = (__hip_bfloat16*)alloc((size_t)1024 * 1024 * 2);
    __hip_bfloat16* EMBp  = (__hip_bfloat16*)alloc((size_t)1024 * 1024 * 2);
    __hip_bfloat16* EMB2  = (__hip_bfloat16*)alloc((size_t)1024 * 1024 * 2);
    __hip_bfloat16* tw1t  = (__hip_bfloat16*)alloc((size_t)1024 * 1024 * 2);
    __hip_bfloat16* tw2t  = (__hip_bfloat16*)alloc((size_t)1024 * 1024 * 2);
    __hip_bfloat16* w1t   = (__hip_bfloat16*)alloc((size_t)1024 * 1024 * 2);
    __hip_bfloat16* w2t   = (__hip_bfloat16*)alloc((size_t)512 * 1024 * 2);
    __hip_bfloat16* pjb   = (__hip_bfloat16*)alloc((size_t)448 * 1024 * 2);
    __hip_bfloat16* PWT   = (__hip_bfloat16*)alloc((size_t)1024 * 416 * 2);
    __hip_bfloat16* X     = (__hip_bfloat16*)alloc((size_t)BATCH * 416 * 2);
    __hip_bfloat16* R     = (__hip_bfloat16*)alloc((size_t)BATCH * 1024 * 2);

    // setup: 4 transposes + pjb cast + E0 table + colconst/zbias + schedules + ltbl
    setup_all<<<7813, 256, 0, stream>>>(te_w1, te_w2, mlp_w1, mlp_w2,
                                        tw1t, tw2t, w1t, w2t, pjb,
                                        E0, proj_w, proj_b, te_b2,
                                        colconst, zbias, sched, ltbl, acc);
    // X + hot
    prep_x<<<BATCH / 16, 256, 0, stream>>>(x_num, x_cat, t_in, noise, gum, sched, X, hot);
    // PWT[j,k] = sum_n w1[n,j] proj_w[k,n]  -> [1024 x 416] bf16
    gemm_mfma<5, 64><<<dim3(7, 16), 256, 0, stream>>>(
        w1t, pjb, zbias, PWT, 1024, 1024, 416, 416,
        nullptr, nullptr, nullptr, nullptr, nullptr, nullptr, nullptr, nullptr);
    // E1 = silu(E0 @ te_w1 + te_b1)
    gemm_mfma<1, 64><<<dim3(16, 16), 256, 0, stream>>>(
        E0, tw1t, te_b1, E1, 1000, 1024, 1024, 1024,
        nullptr, nullptr, nullptr, nullptr, nullptr, nullptr, nullptr, nullptr);
    // EMBp = E1 @ te_w2 + (te_b2 + proj_b + L30F*catsum)   [all h-space consts]
    gemm_mfma<5, 64><<<dim3(16, 16), 256, 0, stream>>>(
        E1, tw2t, colconst, EMBp, 1000, 1024, 1024, 1024,
        nullptr, nullptr, nullptr, nullptr, nullptr, nullptr, nullptr, nullptr);
    // EMB2 = EMBp @ w1 + b1   [per-t hidden-layer bias table]
    gemm_mfma<5, 64><<<dim3(16, 16), 256, 0, stream>>>(
        EMBp, w1t, mlp_b1, EMB2, 1000, 1024, 1024, 1024,
        nullptr, nullptr, nullptr, nullptr, nullptr, nullptr, nullptr, nullptr);
    // R = relu(X @ PWT^T + EMB2[t])   [h-GEMM + R-GEMM collapsed; batched gather]
    gemm_mfma<6, 128><<<dim3(8, 128), 256, 0, stream>>>(
        X, PWT, zbias, R, BATCH, 416, 1024, 1024,
        t_in, (const float*)EMB2, nullptr, nullptr, nullptr, nullptr, nullptr, nullptr);
    // fused: (R @ mlp_w2 + mlp_b2) -> LDS scoreboard -> linear-space loss
    gemm_mfma<4, 64><<<dim3(7, 256), 256, 0, stream>>>(
        R, w2t, mlp_b2, nullptr, BATCH, 1024, 400, 0,
        nullptr, ltbl, x_cat, t_in, hot, noise, sched, acc);
    finalize_kernel<<<1, 1, 0, stream>>>(acc, sched, out);
}